// Round 10
// baseline (906.202 us; speedup 1.0000x reference)
//
#include <hip/hip_runtime.h>

// GCN 2-layer + pool + head. R10: bypass the ~19.6G/s random-RMW wall (R6-R9) by binning
// edges by col>>6 and accumulating in LDS tiles. R3-R5's 12G edges/s consumer cap is
// diagnosed as VGPR starvation (VGPR_Count=16..32 -> serialized gathers), not a memory
// limit: fix with __launch_bounds__(512,2) + explicit 8-deep load batches.
//   h[c] = b + dinv[c]*( g[c] + sum_e w_e * g[row_e] ),  g = dinv * (prev @ W)

#define SH 6
#define RB 64
#define KMAX 2048           // N <= 131072 (row packs in 17 bits)
#define TPB 256

// ---------- bucket counts ----------
__global__ void k_cnt(const int* __restrict__ col, unsigned* __restrict__ bcnt, int E, int K) {
    __shared__ unsigned lh[KMAX];
    for (int i = threadIdx.x; i < K; i += blockDim.x) lh[i] = 0u;
    __syncthreads();
    for (long long e = (long long)blockIdx.x * blockDim.x + threadIdx.x; e < E;
         e += (long long)gridDim.x * blockDim.x)
        atomicAdd(&lh[col[e] >> SH], 1u);
    __syncthreads();
    for (int i = threadIdx.x; i < K; i += blockDim.x)
        if (lh[i]) atomicAdd(&bcnt[i], lh[i]);
}

// ---------- exclusive scan -> bst, bcur ----------
__global__ void k_scan(const unsigned* __restrict__ cnt, unsigned* __restrict__ start,
                       unsigned* __restrict__ cursor, int K) {
    __shared__ unsigned a[KMAX], b[KMAX];
    int t = threadIdx.x;  // 1024
    for (int i = t; i < KMAX; i += 1024) a[i] = (i < K) ? cnt[i] : 0u;
    __syncthreads();
    unsigned *src = a, *dst = b;
    for (int off = 1; off < KMAX; off <<= 1) {
        for (int i = t; i < KMAX; i += 1024)
            dst[i] = (i >= off) ? src[i] + src[i - off] : src[i];
        __syncthreads();
        unsigned* tmp = src; src = dst; dst = tmp;
    }
    for (int i = t; i < K; i += 1024) {
        unsigned ex = (i == 0) ? 0u : src[i - 1];
        start[i] = ex; cursor[i] = ex;
    }
}

// ---------- bin scatter (single LDS array: count -> reserve -> place) ----------
__global__ __launch_bounds__(512)
void k_binsc(const int* __restrict__ row, const int* __restrict__ col,
             const float* __restrict__ w, unsigned* __restrict__ bcur,
             uint2* __restrict__ brcw, int E, int K) {
    __shared__ unsigned lh[KMAX];
    int tile = (E + gridDim.x - 1) / gridDim.x;
    int e0 = blockIdx.x * tile, e1 = min(e0 + tile, E);
    for (int i = threadIdx.x; i < K; i += 512) lh[i] = 0u;
    __syncthreads();
    for (int e = e0 + threadIdx.x; e < e1; e += 512) atomicAdd(&lh[col[e] >> SH], 1u);
    __syncthreads();
    for (int i = threadIdx.x; i < K; i += 512) {
        unsigned c = lh[i];
        lh[i] = c ? atomicAdd(&bcur[i], c) : 0u;   // lh becomes this block's local cursor
    }
    __syncthreads();
    for (int e = e0 + threadIdx.x; e < e1; e += 512) {
        int c = col[e];
        unsigned pos = atomicAdd(&lh[c >> SH], 1u);
        brcw[pos] = make_uint2((unsigned)row[e] | ((unsigned)(c & 63) << 17),
                               __float_as_uint(w[e]));
    }
}

// ---------- per-bucket deg -> dinv, fused with g1 = dinv*(x@W1) ----------
__global__ void k_bdeg_gtab(const uint2* __restrict__ brcw, const unsigned* __restrict__ bst,
                            const unsigned* __restrict__ bcnt, const float* __restrict__ x,
                            const float* __restrict__ W1, float* __restrict__ dinv,
                            float* __restrict__ g1, int N) {
    int k = blockIdx.x, node0 = k << SH;
    __shared__ float dacc[RB], dl[RB], lx[RB * 3], lw[48];
    int tid = threadIdx.x;  // 256
    if (tid < RB) dacc[tid] = 1.0f;               // self-loop weight
    if (tid < 48) lw[tid] = W1[tid];
    int nn = min(RB, N - node0);
    for (int i = tid; i < nn * 3; i += 256) lx[i] = x[(size_t)node0 * 3 + i];
    __syncthreads();
    unsigned s = bst[k], c = bcnt[k];
    for (unsigned j = tid; j < c; j += 256) {
        uint2 p = brcw[s + j];
        atomicAdd(&dacc[(p.x >> 17) & 63u], __uint_as_float(p.y));
    }
    __syncthreads();
    if (tid < RB) {
        float r = rsqrtf(dacc[tid]);
        dl[tid] = r;
        if (tid < nn) dinv[node0 + tid] = r;
    }
    __syncthreads();
    for (int idx = tid; idx < nn * 16; idx += 256) {
        int n = idx >> 4, f = idx & 15;
        float v = lx[n * 3] * lw[f] + lx[n * 3 + 1] * lw[16 + f] + lx[n * 3 + 2] * lw[32 + f];
        g1[(size_t)(node0 + n) * 16 + f] = dl[n] * v;
    }
}

// ---------- consumer: LDS tile accumulate, 8-deep explicit batches ----------
__global__ __launch_bounds__(512, 2)
void k_cons(const uint2* __restrict__ brcw, const unsigned* __restrict__ bst,
            const unsigned* __restrict__ bcnt, const float* __restrict__ g,
            float* __restrict__ hpart, int N) {
    int k = blockIdx.x, sp = blockIdx.y, S = gridDim.y;
    int node0 = k << SH;
    __shared__ float tile[RB * 16];  // 4KB
    int tid = threadIdx.x;
    for (int i = tid; i < RB * 16; i += 512) tile[i] = 0.0f;
    __syncthreads();
    unsigned s = bst[k], c = bcnt[k];
    unsigned cs = (c + S - 1) / S;
    unsigned j0 = (unsigned)sp * cs, j1 = min(j0 + cs, c);
    int slot = tid >> 4, f = tid & 15;   // 32 edge-slots x 16 feature lanes
    const uint2* eb = brcw + s;
    unsigned j = j0 + (unsigned)slot;
    for (; j + 224 < j1; j += 256) {
        uint2 m0 = eb[j],       m1 = eb[j + 32],  m2 = eb[j + 64],  m3 = eb[j + 96];
        uint2 m4 = eb[j + 128], m5 = eb[j + 160], m6 = eb[j + 192], m7 = eb[j + 224];
        float v0 = g[(size_t)(m0.x & 0x1FFFFu) * 16 + f];
        float v1 = g[(size_t)(m1.x & 0x1FFFFu) * 16 + f];
        float v2 = g[(size_t)(m2.x & 0x1FFFFu) * 16 + f];
        float v3 = g[(size_t)(m3.x & 0x1FFFFu) * 16 + f];
        float v4 = g[(size_t)(m4.x & 0x1FFFFu) * 16 + f];
        float v5 = g[(size_t)(m5.x & 0x1FFFFu) * 16 + f];
        float v6 = g[(size_t)(m6.x & 0x1FFFFu) * 16 + f];
        float v7 = g[(size_t)(m7.x & 0x1FFFFu) * 16 + f];
        atomicAdd(&tile[((m0.x >> 17) & 63u) * 16 + f], __uint_as_float(m0.y) * v0);
        atomicAdd(&tile[((m1.x >> 17) & 63u) * 16 + f], __uint_as_float(m1.y) * v1);
        atomicAdd(&tile[((m2.x >> 17) & 63u) * 16 + f], __uint_as_float(m2.y) * v2);
        atomicAdd(&tile[((m3.x >> 17) & 63u) * 16 + f], __uint_as_float(m3.y) * v3);
        atomicAdd(&tile[((m4.x >> 17) & 63u) * 16 + f], __uint_as_float(m4.y) * v4);
        atomicAdd(&tile[((m5.x >> 17) & 63u) * 16 + f], __uint_as_float(m5.y) * v5);
        atomicAdd(&tile[((m6.x >> 17) & 63u) * 16 + f], __uint_as_float(m6.y) * v6);
        atomicAdd(&tile[((m7.x >> 17) & 63u) * 16 + f], __uint_as_float(m7.y) * v7);
    }
    for (; j < j1; j += 32) {
        uint2 m0 = eb[j];
        float v0 = g[(size_t)(m0.x & 0x1FFFFu) * 16 + f];
        atomicAdd(&tile[((m0.x >> 17) & 63u) * 16 + f], __uint_as_float(m0.y) * v0);
    }
    __syncthreads();
    int nn = min(RB, N - node0);
    float* dst = hpart + (size_t)sp * N * 16 + (size_t)node0 * 16;
    for (int i = tid; i < nn * 16; i += 512)
        __builtin_nontemporal_store(tile[i], dst + i);
}

// ---------- mid: h1 = relu(b1 + dinv*(g1 + sum hpart)); g2 = dinv*(h1@W2) ----------
__global__ void k_mid(const float* __restrict__ g1, const float* __restrict__ hpart,
                      const float* __restrict__ dinv, const float* __restrict__ b1,
                      const float* __restrict__ W2, float* __restrict__ g2, int N, int S) {
    __shared__ float t[16][16];
    __shared__ float w2[256];
    int tid = threadIdx.x;
    int il = tid >> 4, f = tid & 15;
    int i = blockIdx.x * 16 + il;
    w2[tid] = W2[tid];
    float v = 0.0f, d = 0.0f;
    if (i < N) {
        d = dinv[i];
        v = g1[(size_t)i * 16 + f];
        for (int s = 0; s < S; s++)
            v += __builtin_nontemporal_load(hpart + (size_t)s * N * 16 + (size_t)i * 16 + f);
        v = b1[f] + d * v;
        v = v > 0.0f ? v : 0.0f;
    }
    t[il][f] = v;
    __syncthreads();
    if (i < N) {
        float o = 0.0f;
#pragma unroll
        for (int kk = 0; kk < 16; kk++) o += t[il][kk] * w2[kk * 16 + f];
        g2[(size_t)i * 16 + f] = d * o;
    }
}

// ---------- pool: h2 = relu(b2 + dinv*(g2 + sum hpart)) folded into sorted-batch pool ----------
#define PC 1024
__global__ void k_pool(const float* __restrict__ g2, const float* __restrict__ hpart,
                       const float* __restrict__ dinv, const float* __restrict__ b2,
                       const int* __restrict__ batch, float* __restrict__ pooled,
                       int N, int G, int S) {
    int b0 = blockIdx.x * PC;
    int nodes = min(PC, N - b0);
    __shared__ float lacc[64 * 16];
    __shared__ int lbat[PC];
    int tid = threadIdx.x;  // 256
    for (int i = tid; i < nodes; i += 256) lbat[i] = batch[b0 + i];
    __syncthreads();
    int gmin = lbat[0], gmax = lbat[nodes - 1];
    bool fits = (gmax - gmin < 64);
    if (fits) {
        for (int i = tid; i < 64 * 16; i += 256) lacc[i] = 0.0f;
        __syncthreads();
    }
    for (int idx = tid; idx < nodes * 16; idx += 256) {
        int i = idx >> 4, f = idx & 15;
        int n = b0 + i;
        float d = dinv[n];
        float v = g2[(size_t)n * 16 + f];
        for (int s = 0; s < S; s++)
            v += __builtin_nontemporal_load(hpart + (size_t)s * N * 16 + (size_t)n * 16 + f);
        v = b2[f] + d * v;
        v = v > 0.0f ? v : 0.0f;
        if (fits) atomicAdd(&lacc[(lbat[i] - gmin) * 16 + f], v);
        else      atomicAdd(&pooled[lbat[i] * 16 + f], v);
    }
    if (fits) {
        __syncthreads();
        for (int idx = tid; idx < 64 * 16; idx += 256) {
            int g = gmin + (idx >> 4);
            float v = lacc[idx];
            if (g < G && v != 0.0f) atomicAdd(&pooled[g * 16 + (idx & 15)], v);
        }
    }
}

__global__ void k_final(const float* __restrict__ pooled, const float* __restrict__ Wlin,
                        const float* __restrict__ blin, float* __restrict__ out, int G) {
    int t = blockIdx.x * blockDim.x + threadIdx.x;
    int g = t / 7, j = t % 7;
    if (g >= G) return;
    float v = blin[j];
#pragma unroll
    for (int f = 0; f < 16; f++) v += pooled[g * 16 + f] * Wlin[f * 7 + j];
    out[g * 7 + j] = v;
}

static inline int cdiv_i(long long a, long long b) { return (int)((a + b - 1) / b); }

extern "C" void kernel_launch(void* const* d_in, const int* in_sizes, int n_in,
                              void* d_out, int out_size, void* d_ws, size_t ws_size,
                              hipStream_t stream) {
    const float* x     = (const float*)d_in[0];
    const int*   ei    = (const int*)d_in[1];
    const float* ew    = (const float*)d_in[2];
    const int*   batch = (const int*)d_in[3];
    const float* W1    = (const float*)d_in[4];
    const float* b1    = (const float*)d_in[5];
    const float* W2    = (const float*)d_in[6];
    const float* b2    = (const float*)d_in[7];
    const float* Wlin  = (const float*)d_in[8];
    const float* blin  = (const float*)d_in[9];
    float* out = (float*)d_out;

    const int N = in_sizes[0] / 3;
    const int E = in_sizes[2];
    const int G = out_size / 7;
    const int K = (N + RB - 1) >> SH;   // 1563
    const int* row = ei;
    const int* col = ei + E;

    // layout: brcw | [zero: bcnt, bcur, pooled] | bst | dinv | g1 | g2 | hpart
    uint2*    brcw   = (uint2*)d_ws;                        // E
    unsigned* bcnt   = (unsigned*)(brcw + E);               // KMAX
    unsigned* bcur   = bcnt + KMAX;                         // KMAX
    float*    pooled = (float*)(bcur + KMAX);               // G*16
    unsigned* bst    = (unsigned*)(pooled + (size_t)G*16);  // KMAX
    float*    dinv   = (float*)(bst + KMAX);                // N
    float*    g1     = dinv + N;                            // N*16
    float*    g2     = g1 + (size_t)N * 16;                 // N*16
    float*    hpart  = g2 + (size_t)N * 16;                 // S*N*16

    size_t fixed = (char*)hpart - (char*)d_ws;
    size_t per_part = (size_t)N * 16 * sizeof(float);
    int S = (int)((ws_size - fixed) / per_part);
    S = S < 1 ? 1 : (S > 4 ? 4 : S);

    hipMemsetAsync(bcnt, 0, (2 * KMAX + (size_t)G * 16) * sizeof(unsigned), stream);

    // bin edges by col>>6
    k_cnt<<<256, TPB, 0, stream>>>(col, bcnt, E, K);
    k_scan<<<1, 1024, 0, stream>>>(bcnt, bst, bcur, K);
    k_binsc<<<64, 512, 0, stream>>>(row, col, ew, bcur, brcw, E, K);

    // bucket-local deg -> dinv, fused g1 = dinv*(x@W1)
    k_bdeg_gtab<<<K, TPB, 0, stream>>>(brcw, bst, bcnt, x, W1, dinv, g1, N);

    // layer 1
    k_cons<<<dim3(K, S), 512, 0, stream>>>(brcw, bst, bcnt, g1, hpart, N);
    k_mid<<<cdiv_i(N, 16), TPB, 0, stream>>>(g1, hpart, dinv, b1, W2, g2, N, S);

    // layer 2
    k_cons<<<dim3(K, S), 512, 0, stream>>>(brcw, bst, bcnt, g2, hpart, N);
    k_pool<<<cdiv_i(N, PC), TPB, 0, stream>>>(g2, hpart, dinv, b2, batch, pooled, N, G, S);

    k_final<<<cdiv_i((long long)G * 7, TPB), TPB, 0, stream>>>(pooled, Wlin, blin, out, G);
}